// Round 1
// baseline (476.355 us; speedup 1.0000x reference)
//
#include <hip/hip_runtime.h>

#define LOG2E 1.4426950408889634f
#define LN2   0.6931471805599453

// B=512, S=1024, n=64, L=66. One wave (64 lanes) per batch element.
// Lane j owns CRF state j. State kept as P[j] = 2^(alpha[j] - M2), M2 in f64.
__global__ __launch_bounds__(64, 1)
void crf_nll_kernel(const float* __restrict__ logits,
                    const float* __restrict__ T,
                    const int* __restrict__ labels,
                    const int* __restrict__ mask,
                    float* __restrict__ out,
                    int B, int S)
{
    const int b = blockIdx.x;
    const int j = threadIdx.x;          // 0..63
    constexpr int L = 66;
    constexpr int START = 64, END = 65;

    __shared__ __align__(16) float Pbuf[64];

    const float* lg  = logits + (size_t)b * S * 64;
    const int*   lab = labels + (size_t)b * S;
    const int*   msk = mask   + (size_t)b * S;

    // ---- expT row for this lane's state: eT[k] = e^{T[j,k]} = 2^{T[j,k]*log2e}
    float eT[64];
    #pragma unroll
    for (int k = 0; k < 64; ++k)
        eT[k] = __builtin_amdgcn_exp2f(T[j * L + k] * LOG2E);
    const float eTend = __builtin_amdgcn_exp2f(T[END * L + j] * LOG2E); // e^{T[end,j]}
    const float Tjs   = T[j * L + START];                               // T[j,start]

    // ---- prephase: sequence length (mask is a prefix of ones) + transition gold,
    //      lane-parallel over timesteps
    int   lensum = 0;
    float tgl = 0.0f;
    for (int t0 = j; t0 < S; t0 += 64) {
        int m = msk[t0];
        lensum += m;
        if (m && t0 > 0) {
            int lc = lab[t0], lp = lab[t0 - 1];
            tgl += T[lc * L + lp];
        }
    }
    #pragma unroll
    for (int off = 32; off; off >>= 1) {
        lensum += __shfl_xor(lensum, off);
        tgl    += __shfl_xor(tgl, off);
    }
    const int len = lensum;             // >= 1 (lengths >= S/2)

    const int lab0    = lab[0];
    const int lablast = lab[len - 1];
    const float tg = tgl + T[lab0 * L + START] + T[END * L + lablast];

    // ---- init (t = 0): alpha[j] = logits[b,0,j] + T[j,start]  (exact in f32)
    float lgt0 = lg[j];
    float g = (j == lab0) ? lgt0 : 0.0f;          // unary gold, t=0
    float a0 = (lgt0 + Tjs) * LOG2E;              // log2 domain
    float M0 = __uint_as_float(__builtin_amdgcn_readfirstlane(__float_as_uint(a0)));
    double M2 = (double)M0;
    float P = __builtin_amdgcn_exp2f(a0 - M0);

    // ---- software-pipelined serial recursion over t = 1..len-1
    int t1 = (len > 1) ? 1 : 0;
    float lgt  = lg[(size_t)t1 * 64 + j];
    int   labc = lab[t1];

    for (int t = 1; t < len; ++t) {
        Pbuf[j] = P;
        __syncthreads();

        // prefetch next step (independent of the P chain)
        int tn = (t + 1 < len) ? (t + 1) : (len - 1);
        float lgt_n = lg[(size_t)tn * 64 + j];
        int   lab_n = lab[tn];

        float expl = __builtin_amdgcn_exp2f(lgt * LOG2E);   // 2^{logit*log2e}
        if (j == labc) g += lgt;                            // unary gold (free)

        // s[j] = sum_k P[k] * expT[j,k] ; P broadcast from LDS (uniform addr)
        const float4* Pv4 = reinterpret_cast<const float4*>(Pbuf);
        float s0 = 0.f, s1 = 0.f, s2 = 0.f, s3 = 0.f;
        #pragma unroll
        for (int r = 0; r < 16; ++r) {
            float4 p = Pv4[r];
            s0 = fmaf(p.x, eT[4*r+0], s0);
            s1 = fmaf(p.y, eT[4*r+1], s1);
            s2 = fmaf(p.z, eT[4*r+2], s2);
            s3 = fmaf(p.w, eT[4*r+3], s3);
        }
        float s = (s0 + s1) + (s2 + s3);

        // renormalize by lane0's s (1 instr, no reduction); bookkeep in M2 (f64)
        float C = __uint_as_float(__builtin_amdgcn_readfirstlane(__float_as_uint(s)));
        P = (s * expl) * __builtin_amdgcn_rcpf(C);
        M2 += (double)__builtin_amdgcn_logf(C);             // log2(C)

        lgt = lgt_n; labc = lab_n;
    }

    // ---- finalize: norm = (M2 + log2(sum_j P[j]*e^{T[end,j]})) * ln2
    float v  = P * eTend;
    float gg = g;
    #pragma unroll
    for (int off = 32; off; off >>= 1) {
        v  += __shfl_xor(v, off);
        gg += __shfl_xor(gg, off);
    }
    double norm = (M2 + (double)__builtin_amdgcn_logf(v)) * LN2;
    if (j == 0) out[b] = (float)(norm - (double)(gg + tg));
}

extern "C" void kernel_launch(void* const* d_in, const int* in_sizes, int n_in,
                              void* d_out, int out_size, void* d_ws, size_t ws_size,
                              hipStream_t stream) {
    const float* logits = (const float*)d_in[0];
    const float* T      = (const float*)d_in[1];
    const int*   labels = (const int*)d_in[2];
    const int*   mask   = (const int*)d_in[3];
    float*       out    = (float*)d_out;

    const int B = out_size;                 // 512
    const int S = in_sizes[2] / B;          // 1024

    crf_nll_kernel<<<dim3(B), dim3(64), 0, stream>>>(logits, T, labels, mask, out, B, S);
}

// Round 2
// 204.827 us; speedup vs baseline: 2.3257x; 2.3257x over previous
//
#include <hip/hip_runtime.h>

#define LOG2E 1.4426950408889634f
#define LN2   0.6931471805599453

__device__ __forceinline__ float bc_first(float x) {
    return __uint_as_float(__builtin_amdgcn_readfirstlane(__float_as_uint(x)));
}

// B blocks of 128 threads: wave 0 runs the forward recursion over t=0..m-1,
// wave 1 runs the backward recursion over t=len-1..m. Z = sum_k A_m[k]*B_m[k].
// State u is kept unnormalized; each step divides by the PREVIOUS step's
// power-of-two scale (exact integer bookkeeping in an SGPR, applied off-chain).
__global__ __launch_bounds__(128)
void crf_nll_kernel(const float* __restrict__ logits,
                    const float* __restrict__ Tm,
                    const int* __restrict__ labels,
                    const int* __restrict__ mask_g,
                    float* __restrict__ out,
                    int B, int S)
{
    const int b   = blockIdx.x;
    const int tid = threadIdx.x;
    const int w   = tid >> 6;          // 0 = forward, 1 = backward
    const int j   = tid & 63;
    constexpr int L = 66, START = 64, END = 65;

    __shared__ __align__(16) float Ubuf[2][64];   // per-wave broadcast buffer
    __shared__ __align__(16) float exch[64];
    __shared__ int   redI[2];
    __shared__ float redF[2];

    const float* lg  = logits + (size_t)b * S * 64;
    const int*   lab = labels + (size_t)b * S;
    const int*   msk = mask_g + (size_t)b * S;

    // ---------- prephase: len + full gold score (unary gather + transitions)
    int   lensum = 0;
    float gsum   = 0.0f;
    for (int t0 = tid; t0 < S; t0 += 128) {
        int mm = msk[t0];
        if (mm) {
            lensum += 1;
            int lc = lab[t0];
            float ga = lg[(size_t)t0 * 64 + lc];            // unary
            if (t0 > 0) ga += Tm[lc * L + lab[t0 - 1]];     // transition
            gsum += ga;
        }
    }
    #pragma unroll
    for (int off = 32; off; off >>= 1) {
        lensum += __shfl_xor(lensum, off);
        gsum   += __shfl_xor(gsum, off);
    }
    if (j == 0) { redI[w] = lensum; redF[w] = gsum; }

    // ---------- expT fragments (forward: row j; backward: column j)
    float eT[64];
    if (w == 0) {
        #pragma unroll
        for (int k = 0; k < 64; ++k)
            eT[k] = __builtin_amdgcn_exp2f(Tm[j * L + k] * LOG2E);
    } else {
        #pragma unroll
        for (int k = 0; k < 64; ++k)
            eT[k] = __builtin_amdgcn_exp2f(Tm[k * L + j] * LOG2E);
    }

    __syncthreads();
    const int   len   = redI[0] + redI[1];
    const float goldp = redF[0] + redF[1];
    const int   m_mid = (len + 1) >> 1;

    float u;
    int   M2i   = 0;        // exact log2-scale accumulator (uniform -> SGPR)
    int   epend = 0;        // pending exponent (matches rprev)
    float rprev = 1.0f;     // reciprocal of previous step's power-of-two scale

    if (w == 0) {
        // ---------------- forward: A_1 init, then t = 1 .. m_mid-1
        const int tmax = m_mid - 1;
        u = __builtin_amdgcn_exp2f((lg[j] + Tm[j * L + START]) * LOG2E);

        auto cl = [&](int t) { t = (t > tmax) ? tmax : t; return (t < 0) ? 0 : t; };
        float r0 = lg[(size_t)cl(1) * 64 + j];
        float r1 = lg[(size_t)cl(2) * 64 + j];
        float r2 = lg[(size_t)cl(3) * 64 + j];
        float r3 = lg[(size_t)cl(4) * 64 + j];
        float r4 = lg[(size_t)cl(5) * 64 + j];
        float r5 = lg[(size_t)cl(6) * 64 + j];

        for (int t = 1; t <= tmax; ++t) {
            Ubuf[0][j] = u;
            asm volatile("s_waitcnt lgkmcnt(0)" ::: "memory");
            float el  = __builtin_amdgcn_exp2f(r0 * LOG2E);
            float fac = el * rprev;                     // off-chain
            const float4* U4 = (const float4*)(&Ubuf[0][0]);
            float s0 = 0.f, s1 = 0.f, s2 = 0.f, s3 = 0.f;
            #pragma unroll
            for (int r = 0; r < 16; ++r) {
                float4 p = U4[r];                       // broadcast read
                s0 = fmaf(p.x, eT[4*r+0], s0);
                s1 = fmaf(p.y, eT[4*r+1], s1);
                s2 = fmaf(p.z, eT[4*r+2], s2);
                s3 = fmaf(p.w, eT[4*r+3], s3);
            }
            float Sv = (s0 + s1) + (s2 + s3);
            u = Sv * fac;                               // apply prev scale + logit
            M2i += epend;                               // SALU, exact
            unsigned E = __builtin_amdgcn_readfirstlane(__float_as_uint(Sv)) >> 23;
            rprev = __uint_as_float((254u - E) << 23);  // 2^-(E-127), exact
            epend = (int)E - 127;
            r0 = r1; r1 = r2; r2 = r3; r3 = r4; r4 = r5;
            r5 = lg[(size_t)cl(t + 6) * 64 + j];
        }
    } else {
        // ---------------- backward: B_len init (+ logit_{len-1}), t = len-1 .. m_mid
        const int n_b = len - m_mid;
        float initl = (n_b > 0) ? lg[(size_t)(len - 1) * 64 + j] : 0.0f;
        u = __builtin_amdgcn_exp2f((Tm[END * L + j] + initl) * LOG2E);

        auto clb = [&](int idx) { return (idx < 0) ? 0 : idx; };
        float r0 = lg[(size_t)clb(len - 2) * 64 + j];
        float r1 = lg[(size_t)clb(len - 3) * 64 + j];
        float r2 = lg[(size_t)clb(len - 4) * 64 + j];
        float r3 = lg[(size_t)clb(len - 5) * 64 + j];
        float r4 = lg[(size_t)clb(len - 6) * 64 + j];
        float r5 = lg[(size_t)clb(len - 7) * 64 + j];

        for (int i = 0; i < n_b; ++i) {
            Ubuf[1][j] = u;
            asm volatile("s_waitcnt lgkmcnt(0)" ::: "memory");
            float el  = (i < n_b - 1) ? __builtin_amdgcn_exp2f(r0 * LOG2E) : 1.0f;
            float fac = el * rprev;
            const float4* U4 = (const float4*)(&Ubuf[1][0]);
            float s0 = 0.f, s1 = 0.f, s2 = 0.f, s3 = 0.f;
            #pragma unroll
            for (int r = 0; r < 16; ++r) {
                float4 p = U4[r];
                s0 = fmaf(p.x, eT[4*r+0], s0);
                s1 = fmaf(p.y, eT[4*r+1], s1);
                s2 = fmaf(p.z, eT[4*r+2], s2);
                s3 = fmaf(p.w, eT[4*r+3], s3);
            }
            float Sv = (s0 + s1) + (s2 + s3);
            u = Sv * fac;
            M2i += epend;
            unsigned E = __builtin_amdgcn_readfirstlane(__float_as_uint(Sv)) >> 23;
            rprev = __uint_as_float((254u - E) << 23);
            epend = (int)E - 127;
            r0 = r1; r1 = r2; r2 = r3; r3 = r4; r4 = r5;
            r5 = lg[(size_t)clb(len - 2 - (i + 6)) * 64 + j];
        }
    }

    // ---------- combine: Z = ln2 * (M2f + M2b + log2( sum_k uf[k]*ub[k] ))
    if (w == 1) {
        exch[j] = u;
        if (j == 0) redI[1] = M2i;
    }
    __syncthreads();
    if (w == 0) {
        float v = u * exch[j];
        #pragma unroll
        for (int off = 32; off; off >>= 1) v += __shfl_xor(v, off);
        if (j == 0) {
            int    Msum = M2i + redI[1];
            double Z    = ((double)Msum + (double)__builtin_amdgcn_logf(v)) * LN2;
            int lab0 = lab[0];
            int labl = lab[len - 1];
            float goldall = goldp + Tm[lab0 * L + START] + Tm[END * L + labl];
            out[b] = (float)(Z - (double)goldall);
        }
    }
}

extern "C" void kernel_launch(void* const* d_in, const int* in_sizes, int n_in,
                              void* d_out, int out_size, void* d_ws, size_t ws_size,
                              hipStream_t stream) {
    const float* logits = (const float*)d_in[0];
    const float* Tm     = (const float*)d_in[1];
    const int*   labels = (const int*)d_in[2];
    const int*   mask   = (const int*)d_in[3];
    float*       out    = (float*)d_out;

    const int B = out_size;                 // 512
    const int S = in_sizes[2] / B;          // 1024

    crf_nll_kernel<<<dim3(B), dim3(128), 0, stream>>>(logits, Tm, labels, mask, out, B, S);
}

// Round 4
// 187.448 us; speedup vs baseline: 2.5413x; 1.0927x over previous
//
#include <hip/hip_runtime.h>

typedef float f2 __attribute__((ext_vector_type(2)));

#define LOG2E 1.4426950408889634f
#define LN2   0.6931471805599453

// B blocks x 128 threads. Wave 0: forward recursion t=0..m-1; wave 1: backward
// recursion t=len-1..m. Z = sum_k A_m[k]*B_m[k]. State u unnormalized; each
// step divides by the PREVIOUS step's power-of-two scale (exact integer
// bookkeeping, applied off the critical chain). Logits prefetched in batches
// of 8 into ping-pong register arrays (no per-step vmcnt stall).
__global__ __launch_bounds__(128, 1)
void crf_nll_kernel(const float* __restrict__ logits,
                    const float* __restrict__ Tm,
                    const int* __restrict__ labels,
                    const int* __restrict__ mask_g,
                    float* __restrict__ out,
                    int B, int S)
{
    const int b   = blockIdx.x;
    const int tid = threadIdx.x;
    const int w   = tid >> 6;          // 0 = forward, 1 = backward
    const int j   = tid & 63;
    constexpr int L = 66, START = 64, END = 65;

    __shared__ __align__(16) float Ubuf[2][64];
    __shared__ __align__(16) float exch[64];
    __shared__ int   redI[2];
    __shared__ float redF[2];
    __shared__ int   redM;

    const float* lg  = logits + (size_t)b * S * 64;
    const int*   lab = labels + (size_t)b * S;
    const int*   msk = mask_g + (size_t)b * S;

    // ---------- prephase: len + full gold score (unary gather + transitions)
    int   lensum = 0;
    float gsum   = 0.0f;
    for (int t0 = tid; t0 < S; t0 += 128) {
        if (msk[t0]) {
            ++lensum;
            int lc = lab[t0];
            float ga = lg[(size_t)t0 * 64 + lc];
            if (t0 > 0) ga += Tm[lc * L + lab[t0 - 1]];
            gsum += ga;
        }
    }
    #pragma unroll
    for (int off = 32; off; off >>= 1) {
        lensum += __shfl_xor(lensum, off);
        gsum   += __shfl_xor(gsum, off);
    }
    if (j == 0) { redI[w] = lensum; redF[w] = gsum; }

    // ---------- expT fragments as f2 pairs (fwd: row j; bwd: column j)
    f2 eT[32];
    if (w == 0) {
        #pragma unroll
        for (int r = 0; r < 32; ++r) {
            f2 v = { __builtin_amdgcn_exp2f(Tm[j * L + 2*r]     * LOG2E),
                     __builtin_amdgcn_exp2f(Tm[j * L + 2*r + 1] * LOG2E) };
            eT[r] = v;
        }
    } else {
        #pragma unroll
        for (int r = 0; r < 32; ++r) {
            f2 v = { __builtin_amdgcn_exp2f(Tm[(2*r)     * L + j] * LOG2E),
                     __builtin_amdgcn_exp2f(Tm[(2*r + 1) * L + j] * LOG2E) };
            eT[r] = v;
        }
    }

    __syncthreads();
    const int   len   = redI[0] + redI[1];
    const float goldp = redF[0] + redF[1];
    const int   m_mid = (len + 1) >> 1;

    float u;
    int   M2i   = 0;        // exact log2-scale accumulator (uniform -> SGPR)
    int   epend = 0;        // pending exponent (matches rprev)
    float rprev = 1.0f;     // reciprocal of previous step's power-of-two scale

    auto STEP = [&](float lv, bool useEl) {
        Ubuf[w][j] = u;
        float el  = useEl ? __builtin_amdgcn_exp2f(lv * LOG2E) : 1.0f;
        float fac = el * rprev;                         // off-chain
        const float4* U4 = (const float4*)(&Ubuf[w][0]);
        f2 a0 = {0.f, 0.f}, a1 = {0.f, 0.f}, a2 = {0.f, 0.f}, a3 = {0.f, 0.f};
        #pragma unroll
        for (int i = 0; i < 8; ++i) {
            float4 p = U4[2*i];                         // broadcast reads
            float4 q = U4[2*i + 1];
            f2 p0 = {p.x, p.y}, p1 = {p.z, p.w};
            f2 q0 = {q.x, q.y}, q1 = {q.z, q.w};
            a0 = __builtin_elementwise_fma(p0, eT[4*i + 0], a0);
            a1 = __builtin_elementwise_fma(p1, eT[4*i + 1], a1);
            a2 = __builtin_elementwise_fma(q0, eT[4*i + 2], a2);
            a3 = __builtin_elementwise_fma(q1, eT[4*i + 3], a3);
        }
        f2 s01 = a0 + a1, s23 = a2 + a3, sv2 = s01 + s23;
        float Sv = sv2.x + sv2.y;
        u = Sv * fac;                                   // apply prev scale + logit
        M2i += epend;                                   // SALU, exact
        unsigned E = __builtin_amdgcn_readfirstlane(__float_as_uint(Sv)) >> 23;
        rprev = __uint_as_float((254u - E) << 23);      // 2^-(E-127), exact
        epend = (int)E - 127;
    };

    if (w == 0) {
        // ---------------- forward: A_1 init, then steps t = 1 .. tmax
        const int tmax = m_mid - 1;
        u = __builtin_amdgcn_exp2f((lg[j] + Tm[j * L + START]) * LOG2E);
        auto ldf = [&](int t) {
            t = (t > tmax) ? tmax : t; t = (t < 1) ? 1 : t;
            return lg[(size_t)t * 64 + j];
        };
        float La[8], Lb[8];
        #pragma unroll
        for (int q = 0; q < 8; ++q) La[q] = ldf(1 + q);
        int base = 1;
        for (; base + 15 <= tmax; base += 16) {
            #pragma unroll
            for (int q = 0; q < 8; ++q) Lb[q] = ldf(base + 8 + q);
            #pragma unroll
            for (int q = 0; q < 8; ++q) STEP(La[q], true);
            #pragma unroll
            for (int q = 0; q < 8; ++q) La[q] = ldf(base + 16 + q);
            #pragma unroll
            for (int q = 0; q < 8; ++q) STEP(Lb[q], true);
        }
        int rem = tmax - base + 1;                      // 0..15
        if (rem >= 8) {
            #pragma unroll
            for (int q = 0; q < 8; ++q) Lb[q] = ldf(base + 8 + q);
            #pragma unroll
            for (int q = 0; q < 8; ++q) STEP(La[q], true);
            base += 8; rem -= 8;
            #pragma unroll
            for (int q = 0; q < 8; ++q) { if (q < rem) STEP(Lb[q], true); }
        } else {
            #pragma unroll
            for (int q = 0; q < 8; ++q) { if (q < rem) STEP(La[q], true); }
        }
    } else {
        // ---------------- backward: B_len init (+ logit_{len-1}), n_b steps
        const int n_b = len - m_mid;
        float initl = (n_b > 0) ? lg[(size_t)(len - 1) * 64 + j] : 0.0f;
        u = __builtin_amdgcn_exp2f((Tm[END * L + j] + initl) * LOG2E);
        auto ldb = [&](int i) {
            int idx = len - 2 - i; idx = (idx < 0) ? 0 : idx;
            return lg[(size_t)idx * 64 + j];
        };
        float La[8], Lb[8];
        #pragma unroll
        for (int q = 0; q < 8; ++q) La[q] = ldb(q);
        int base = 0;
        for (; base + 15 <= n_b - 1; base += 16) {
            #pragma unroll
            for (int q = 0; q < 8; ++q) Lb[q] = ldb(base + 8 + q);
            #pragma unroll
            for (int q = 0; q < 8; ++q) STEP(La[q], base + q < n_b - 1);
            #pragma unroll
            for (int q = 0; q < 8; ++q) La[q] = ldb(base + 16 + q);
            #pragma unroll
            for (int q = 0; q < 8; ++q) STEP(Lb[q], base + 8 + q < n_b - 1);
        }
        int rem = n_b - base;                           // 0..15
        if (rem >= 8) {
            #pragma unroll
            for (int q = 0; q < 8; ++q) Lb[q] = ldb(base + 8 + q);
            #pragma unroll
            for (int q = 0; q < 8; ++q) STEP(La[q], base + q < n_b - 1);
            base += 8; rem -= 8;
            #pragma unroll
            for (int q = 0; q < 8; ++q) { if (q < rem) STEP(Lb[q], base + q < n_b - 1); }
        } else {
            #pragma unroll
            for (int q = 0; q < 8; ++q) { if (q < rem) STEP(La[q], base + q < n_b - 1); }
        }
    }

    // ---------- combine: Z = ln2 * (M2f + M2b + log2( sum_k uf[k]*ub[k] ))
    if (w == 1) {
        exch[j] = u;
        if (j == 0) redM = M2i;
    }
    __syncthreads();
    if (w == 0) {
        float v = u * exch[j];
        #pragma unroll
        for (int off = 32; off; off >>= 1) v += __shfl_xor(v, off);
        if (j == 0) {
            int    Msum = M2i + redM;
            double Z    = ((double)Msum + (double)__builtin_amdgcn_logf(v)) * LN2;
            int lab0 = lab[0];
            int labl = lab[len - 1];
            float goldall = goldp + Tm[lab0 * L + START] + Tm[END * L + labl];
            out[b] = (float)(Z - (double)goldall);
        }
    }
}

extern "C" void kernel_launch(void* const* d_in, const int* in_sizes, int n_in,
                              void* d_out, int out_size, void* d_ws, size_t ws_size,
                              hipStream_t stream) {
    const float* logits = (const float*)d_in[0];
    const float* Tm     = (const float*)d_in[1];
    const int*   labels = (const int*)d_in[2];
    const int*   mask   = (const int*)d_in[3];
    float*       out    = (float*)d_out;

    const int B = out_size;                 // 512
    const int S = in_sizes[2] / B;          // 1024

    crf_nll_kernel<<<dim3(B), dim3(128), 0, stream>>>(logits, Tm, labels, mask, out, B, S);
}